// Round 3
// baseline (204.900 us; speedup 1.0000x reference)
//
#include <hip/hip_runtime.h>

// Problem constants (from reference): B=8, N=128, D=256, C=3
#define BB 8
#define NN 128
#define DD 256
#define NF4 (DD / 4)   // 64 float4 per (b,n,m) row

// Single fused dispatch: one block per (b,n), 512 threads (8 waves; 4 blk/CU
// -> 32 waves/CU). Streams the 128 KB s_e[b,n,:,:] row with float4 loads
// (each thread: 16 loads, 2 independent accumulators), block-reduces over m,
// fuses N*s_v + the per-(b,n) weight, then accumulates the weighted partial
// directly into out[b,:] with native fp32 atomics (unsafeAtomicAdd ->
// global_atomic_add_f32; device scope, executed near-memory). The harness
// zeroes `out` before the verified launch, so atomic accumulation is exact
// up to fp32 add reordering (~1e-6 vs ~2e-3 threshold).
//
// lam_b score2 loads are issued non-blocking at entry (wave 0) and reduced
// only after the stream loop, so no barrier precedes the first HBM load.
__global__ __launch_bounds__(512) void fused_kernel(
    const float4* __restrict__ se4,       // (B,N,N,D) as float4
    const float4* __restrict__ sv4,       // (B,N,D)   as float4
    const float4* __restrict__ score4,    // (B,3,N) as float4: 96 per b
    const float*  __restrict__ se_score,  // (B,3,N) scalar view
    const int*    __restrict__ sub_graph, // (B,)
    const float*  __restrict__ num_node,  // (B,)
    float* __restrict__ out)              // (B,D) fp32, pre-zeroed
{
    const int blk = blockIdx.x;      // 0..1023
    const int b   = blk >> 7;
    const int n   = blk & 127;
    const int tid = threadIdx.x;     // 0..511
    const int v   = tid & 63;        // float4 column (d/4)
    const int s   = tid >> 6;        // m-slice / wave id 0..7

    // Issue score2 loads early (wave 0 only, 64 float4 = 256 floats, L2-hot).
    float4 sc4 = make_float4(0.f, 0.f, 0.f, 0.f);
    if (tid < 64) sc4 = score4[b * 96 + tid];

    // ---- main stream: reduce s_e[b,n,:,:] over m. m = s + 8*i, i=0..15.
    const float4* __restrict__ p =
        se4 + (size_t)(b * NN + n) * (NN * NF4) + (size_t)s * NF4 + v;

    float4 a0 = make_float4(0.f, 0.f, 0.f, 0.f);
    float4 a1 = make_float4(0.f, 0.f, 0.f, 0.f);
    #pragma unroll
    for (int i = 0; i < 16; i += 2) {
        const float4 x = p[(size_t)(i    ) * 8 * NF4];
        const float4 y = p[(size_t)(i + 1) * 8 * NF4];
        a0.x += x.x; a0.y += x.y; a0.z += x.z; a0.w += x.w;
        a1.x += y.x; a1.y += y.y; a1.z += y.z; a1.w += y.w;
    }
    float4 a;
    a.x = a0.x + a1.x; a.y = a0.y + a1.y;
    a.z = a0.z + a1.z; a.w = a0.w + a1.w;

    __shared__ float4 sm[512];
    __shared__ float lamb_sh;
    sm[tid] = a;

    // Deferred lam_b reduce (wave 0), overlapped with other waves' sm stores.
    if (tid < 64) {
        float x = sc4.x + sc4.y + sc4.z + sc4.w;
        #pragma unroll
        for (int off = 32; off > 0; off >>= 1)
            x += __shfl_down(x, off, 64);
        if (tid == 0) lamb_sh = x + 1e-6f;
    }
    __syncthreads();

    if (tid < 64) {
        float4 t = sm[tid];
        #pragma unroll
        for (int k = 1; k < 8; ++k) {
            const float4 u = sm[tid + 64 * k];
            t.x += u.x; t.y += u.y; t.z += u.z; t.w += u.w;
        }

        // per-(b,n) weight (wave-uniform; broadcast loads, L2-hot)
        const float sc   = se_score[b * 3 * NN + n] + se_score[b * 3 * NN + NN + n];
        const float mask = (sub_graph[b] == n && n != 0) ? 1.0f : 0.0f;
        const float nnum = num_node[b];
        const float w    = (sc + mask) / (lamb_sh * nnum * nnum);

        const float4 sv = sv4[(size_t)(b * NN + n) * NF4 + v];

        // weighted partial for this (b,n): accumulate straight into out[b,:]
        float* dst = out + b * DD + v * 4;
        unsafeAtomicAdd(dst + 0, w * (128.0f * sv.x + t.x));
        unsafeAtomicAdd(dst + 1, w * (128.0f * sv.y + t.y));
        unsafeAtomicAdd(dst + 2, w * (128.0f * sv.z + t.z));
        unsafeAtomicAdd(dst + 3, w * (128.0f * sv.w + t.w));
    }
}

extern "C" void kernel_launch(void* const* d_in, const int* in_sizes, int n_in,
                              void* d_out, int out_size, void* d_ws, size_t ws_size,
                              hipStream_t stream) {
    const float* s_v       = (const float*)d_in[0];  // (B,N,D)
    const float* s_e       = (const float*)d_in[1];  // (B,N,N,D)
    const int*   sub_graph = (const int*)  d_in[2];  // (B,)
    const float* s_e_score = (const float*)d_in[3];  // (B,3,N)
    const float* num_node  = (const float*)d_in[4];  // (B,)

    fused_kernel<<<BB * NN, 512, 0, stream>>>(
        (const float4*)s_e, (const float4*)s_v, (const float4*)s_e_score,
        s_e_score, sub_graph, num_node, (float*)d_out);
}

// Round 4
// 188.580 us; speedup vs baseline: 1.0865x; 1.0865x over previous
//
#include <hip/hip_runtime.h>

// Problem constants (from reference): B=8, N=128, D=256, C=3
#define BB 8
#define NN 128
#define DD 256
#define NF4 (DD / 4)   // 64 float4 per (b,n,m) row

typedef float f32x4 __attribute__((ext_vector_type(4)));

// Pass 1: one block per (b,n), 512 threads (8 waves -> 32 waves/CU at 4
// blocks/CU). Streams the 128 KB s_e[b,n,:,:] row with NON-TEMPORAL float4
// loads (read-once data; nt avoids L1/L2 retention churn on the streaming
// front), reduces over m, fuses N*s_v + per-(b,n) weight, writes the 1 KB
// weighted partial to ws with NORMAL stores (pass2 reads them L2-hot).
// lam_b score2 loads are issued non-blocking at entry (wave 0) and reduced
// after the stream loop, so no barrier precedes the first HBM load.
__global__ __launch_bounds__(512) void pass1_kernel(
    const f32x4* __restrict__ se4,        // (B,N,N,D) as float4
    const float4* __restrict__ sv4,       // (B,N,D)   as float4
    const float4* __restrict__ score4,    // (B,3,N) as float4: 96 per b
    const float*  __restrict__ se_score,  // (B,3,N) scalar view
    const int*    __restrict__ sub_graph, // (B,)
    const float*  __restrict__ num_node,  // (B,)
    float4* __restrict__ ws4)             // (B,N,D) partials as float4
{
    const int blk = blockIdx.x;      // 0..1023
    const int b   = blk >> 7;
    const int n   = blk & 127;
    const int tid = threadIdx.x;     // 0..511
    const int v   = tid & 63;        // float4 column (d/4)
    const int s   = tid >> 6;        // m-slice / wave id 0..7

    // Issue score2 loads early (wave 0 only, 64 float4 = 256 floats, L2-hot).
    float4 sc4 = make_float4(0.f, 0.f, 0.f, 0.f);
    if (tid < 64) sc4 = score4[b * 96 + tid];

    // ---- main stream: reduce s_e[b,n,:,:] over m. m = s + 8*i, i=0..15.
    const f32x4* __restrict__ p =
        se4 + (size_t)(b * NN + n) * (NN * NF4) + (size_t)s * NF4 + v;

    f32x4 a0 = (f32x4)(0.f);
    f32x4 a1 = (f32x4)(0.f);
    #pragma unroll
    for (int i = 0; i < 16; i += 2) {
        const f32x4 x = __builtin_nontemporal_load(p + (size_t)(i    ) * 8 * NF4);
        const f32x4 y = __builtin_nontemporal_load(p + (size_t)(i + 1) * 8 * NF4);
        a0 += x;
        a1 += y;
    }
    const f32x4 a = a0 + a1;

    __shared__ f32x4 sm[512];
    __shared__ float lamb_sh;
    sm[tid] = a;

    // Deferred lam_b reduce (wave 0), overlapped with other waves' sm stores.
    if (tid < 64) {
        float x = sc4.x + sc4.y + sc4.z + sc4.w;
        #pragma unroll
        for (int off = 32; off > 0; off >>= 1)
            x += __shfl_down(x, off, 64);
        if (tid == 0) lamb_sh = x + 1e-6f;
    }
    __syncthreads();

    if (tid < 64) {
        f32x4 t = sm[tid];
        #pragma unroll
        for (int k = 1; k < 8; ++k)
            t += sm[tid + 64 * k];

        // per-(b,n) weight (wave-uniform; broadcast loads, L2-hot)
        const float sc   = se_score[b * 3 * NN + n] + se_score[b * 3 * NN + NN + n];
        const float mask = (sub_graph[b] == n && n != 0) ? 1.0f : 0.0f;
        const float nnum = num_node[b];
        const float w    = (sc + mask) / (lamb_sh * nnum * nnum);

        const float4 sv = sv4[(size_t)(b * NN + n) * NF4 + v];

        float4 r;
        r.x = w * (128.0f * sv.x + t[0]);
        r.y = w * (128.0f * sv.y + t[1]);
        r.z = w * (128.0f * sv.z + t[2]);
        r.w = w * (128.0f * sv.w + t[3]);

        ws4[(size_t)(b * NN + n) * NF4 + v] = r;   // coalesced 1 KB store
    }
}

// Pass 2: out[b,d] = sum_n ws[b,n,d]. 8 blocks x 512 threads.
// tid = part(8) x float4-col(64): each thread sums 16 n-rows of one float4
// column, LDS-combines the 8 parts, 64 threads store float4 to out.
__global__ __launch_bounds__(512) void pass2_kernel(
    const float4* __restrict__ ws4,   // (B,N,D) as float4
    float4* __restrict__ out4)        // (B,D) as float4
{
    const int b    = blockIdx.x;
    const int tid  = threadIdx.x;
    const int v    = tid & 63;
    const int part = tid >> 6;        // 0..7

    const float4* __restrict__ p = ws4 + (size_t)b * NN * NF4;

    float4 a = make_float4(0.f, 0.f, 0.f, 0.f);
    #pragma unroll
    for (int n = part * 16; n < part * 16 + 16; ++n) {
        const float4 x = p[n * NF4 + v];
        a.x += x.x; a.y += x.y; a.z += x.z; a.w += x.w;
    }

    __shared__ float4 sm[512];
    sm[tid] = a;
    __syncthreads();

    if (tid < 64) {
        float4 t = sm[tid];
        #pragma unroll
        for (int k = 1; k < 8; ++k) {
            const float4 u = sm[tid + 64 * k];
            t.x += u.x; t.y += u.y; t.z += u.z; t.w += u.w;
        }
        out4[b * NF4 + v] = t;
    }
}

extern "C" void kernel_launch(void* const* d_in, const int* in_sizes, int n_in,
                              void* d_out, int out_size, void* d_ws, size_t ws_size,
                              hipStream_t stream) {
    const float* s_v       = (const float*)d_in[0];  // (B,N,D)
    const float* s_e       = (const float*)d_in[1];  // (B,N,N,D)
    const int*   sub_graph = (const int*)  d_in[2];  // (B,)
    const float* s_e_score = (const float*)d_in[3];  // (B,3,N)
    const float* num_node  = (const float*)d_in[4];  // (B,)
    float4* out4 = (float4*)d_out;                   // (B,1,D) fp32
    float4* ws4  = (float4*)d_ws;                    // B*N*D floats = 1 MB

    pass1_kernel<<<BB * NN, 512, 0, stream>>>(
        (const f32x4*)s_e, (const float4*)s_v, (const float4*)s_e_score,
        s_e_score, sub_graph, num_node, ws4);
    pass2_kernel<<<BB, 512, 0, stream>>>(ws4, out4);
}